// Round 6
// baseline (71.063 us; speedup 1.0000x reference)
//
#include <hip/hip_runtime.h>
#include <hip/hip_bf16.h>
#include <stdint.h>

typedef unsigned short u16;
typedef unsigned int   u32;

#define NB   64
#define NN   4096
#define ND   256
#define NTRI 32896   // 256*257/2
#define NSPLIT 4     // n-splits per batch
#define KROWS  1024  // rows per split
#define NCHUNK 16    // chunks per split (64 rows each)

// ---------- helpers ----------
__device__ __forceinline__ u32 cvtpk(float lo, float hi) {
  u32 r;
  asm("v_cvt_pk_bf16_f32 %0, %1, %2" : "=v"(r) : "v"(lo), "v"(hi));
  return r;
}

typedef __attribute__((ext_vector_type(8))) __bf16 bf16x8;
typedef __attribute__((ext_vector_type(4))) float  f32x4;

// ---------- fused: fp32 stream -> bf16 LDS transpose -> MFMA SYRK ----------
// grid = NB*NSPLIT = 256 blocks, 768 thr (12 waves).
// Depth-2 load pipeline: two named staging sets (sA: even chunks, sB: odd);
// ISSUE placed after COMPUTE (sched_barrier-pinned) so the freed set stays
// dead during compute (VGPR peak ~145 < 170 cap @ 12 waves/CU).
__global__ __launch_bounds__(768) void k_cov(const float* __restrict__ in,
                                             float* __restrict__ covp,
                                             float* __restrict__ part) {
  __shared__ alignas(16) u16 Lt[2][2][256][32];   // 64 KB (2 buffers)
  __shared__ float msum[8][256];                  // 8 KB

  int blk = blockIdx.x;
  int b = blk >> 2, s = blk & 3;
  int t = threadIdx.x;
  int w = t >> 6, lane = t & 63;

  // compute roles: 12 waves = 3 triu tiles x 4 quadrants of 64x64
  int tsel = w >> 2;               // 0:(0,0) 1:(0,1) 2:(1,1)
  int quad = w & 3;
  int wr = quad >> 1, wc = quad & 1;
  int ti = (tsel == 2) ? 1 : 0;
  int tj = (tsel == 0) ? 0 : 1;
  bool diag = (ti == tj);
  bool alive = !(diag && quad == 2);   // (1,0) quadrant of diag tile: redundant
  int fr = lane & 15, fg = lane >> 4;
  int dpA = ti * 128 + wr * 64;
  int dpB = tj * 128 + wc * 64;

  // frag byte offsets within a [256][32] plane (16 KB)
  int aoffB[4], boffB[4];
  int jj = (fg ^ (fr >> 2)) << 4;
#pragma unroll
  for (int m = 0; m < 4; ++m) aoffB[m] = (dpA + m * 16 + fr) * 64 + jj;
#pragma unroll
  for (int n = 0; n < 4; ++n) boffB[n] = (dpB + n * 16 + fr) * 64 + jj;

  // staging roles (waves 0..7): wave w covers n_local rows w*8..w*8+7
  bool stager = (w < 8);
  int c4 = lane;                   // d-quad owned during cvt (rows d=4*c4+e)
  int ksw = w >> 2;                // ks-plane this wave fills (0/1)
  int xw = w & 3;                  // 16B n-chunk within plane
  int swz = ((xw ^ (c4 & 3)) << 4);

  f32x4 acc[4][4];
  f32x4 zero = {0.f, 0.f, 0.f, 0.f};
#pragma unroll
  for (int m = 0; m < 4; ++m)
#pragma unroll
    for (int n = 0; n < 4; ++n) acc[m][n] = zero;

  const float4* in4 = (const float4*)(in + (size_t)b * NN * ND);
  int rbase0 = (s * KROWS + w * 8) * 64 + c4;   // float4 index of chunk-0 row0

  float4 ms = make_float4(0.f, 0.f, 0.f, 0.f);
  float4 a0, a1, a2, a3, a4, a5, a6, a7;        // set A (even chunks)
  float4 b0, b1, b2, b3, b4, b5, b6, b7;        // set B (odd chunks)

#define ISSUE_A(C)                                              \
  if (stager) {                                                 \
    int rb = rbase0 + (C) * 4096;                               \
    a0 = in4[rb + 0 * 64]; a1 = in4[rb + 1 * 64];               \
    a2 = in4[rb + 2 * 64]; a3 = in4[rb + 3 * 64];               \
    a4 = in4[rb + 4 * 64]; a5 = in4[rb + 5 * 64];               \
    a6 = in4[rb + 6 * 64]; a7 = in4[rb + 7 * 64];               \
  }

#define ISSUE_B(C)                                              \
  if (stager) {                                                 \
    int rb = rbase0 + (C) * 4096;                               \
    b0 = in4[rb + 0 * 64]; b1 = in4[rb + 1 * 64];               \
    b2 = in4[rb + 2 * 64]; b3 = in4[rb + 3 * 64];               \
    b4 = in4[rb + 4 * 64]; b5 = in4[rb + 5 * 64];               \
    b6 = in4[rb + 6 * 64]; b7 = in4[rb + 7 * 64];               \
  }

// convert set REG0..7 and write to LDS buffer BUF (A -> buf0, B -> buf1)
#define CVT_WRITE(BUF, r0, r1, r2, r3, r4, r5, r6, r7)                        \
  if (stager) {                                                               \
    ms.x += r0.x + r1.x + r2.x + r3.x + r4.x + r5.x + r6.x + r7.x;            \
    ms.y += r0.y + r1.y + r2.y + r3.y + r4.y + r5.y + r6.y + r7.y;            \
    ms.z += r0.z + r1.z + r2.z + r3.z + r4.z + r5.z + r6.z + r7.z;            \
    ms.w += r0.w + r1.w + r2.w + r3.w + r4.w + r5.w + r6.w + r7.w;            \
    char* pl = (char*)&Lt[BUF][ksw][0][0] + swz;                              \
    *(uint4*)(pl + (c4 * 4 + 0) * 64) =                                       \
      make_uint4(cvtpk(r0.x, r1.x), cvtpk(r2.x, r3.x),                        \
                 cvtpk(r4.x, r5.x), cvtpk(r6.x, r7.x));                       \
    *(uint4*)(pl + (c4 * 4 + 1) * 64) =                                       \
      make_uint4(cvtpk(r0.y, r1.y), cvtpk(r2.y, r3.y),                        \
                 cvtpk(r4.y, r5.y), cvtpk(r6.y, r7.y));                       \
    *(uint4*)(pl + (c4 * 4 + 2) * 64) =                                       \
      make_uint4(cvtpk(r0.z, r1.z), cvtpk(r2.z, r3.z),                        \
                 cvtpk(r4.z, r5.z), cvtpk(r6.z, r7.z));                       \
    *(uint4*)(pl + (c4 * 4 + 3) * 64) =                                       \
      make_uint4(cvtpk(r0.w, r1.w), cvtpk(r2.w, r3.w),                        \
                 cvtpk(r4.w, r5.w), cvtpk(r6.w, r7.w));                       \
  }

#define CVT_WRITE_A() CVT_WRITE(0, a0, a1, a2, a3, a4, a5, a6, a7)
#define CVT_WRITE_B() CVT_WRITE(1, b0, b1, b2, b3, b4, b5, b6, b7)

#define COMPUTE(BUF)                                                          \
  if (alive) {                                                                \
    _Pragma("unroll")                                                         \
    for (int ks = 0; ks < 2; ++ks) {                                          \
      const char* pl = (const char*)&Lt[BUF][ks][0][0];                       \
      bf16x8 af[4], bfv[4];                                                   \
      _Pragma("unroll")                                                       \
      for (int m = 0; m < 4; ++m) af[m] = *(const bf16x8*)(pl + aoffB[m]);    \
      _Pragma("unroll")                                                       \
      for (int n = 0; n < 4; ++n) bfv[n] = *(const bf16x8*)(pl + boffB[n]);   \
      _Pragma("unroll")                                                       \
      for (int m = 0; m < 4; ++m)                                             \
        _Pragma("unroll")                                                     \
        for (int n = 0; n < 4; ++n)                                           \
          acc[m][n] = __builtin_amdgcn_mfma_f32_16x16x32_bf16(                \
              af[m], bfv[n], acc[m][n], 0, 0, 0);                             \
    }                                                                         \
  }

  // prologue: chunks 0(A),1(B) issued; chunk0 staged; chunk2(A) issued
  ISSUE_A(0);
  ISSUE_B(1);
  CVT_WRITE_A();                 // chunk 0 -> buf0 (waits A; B stays in flight)
  ISSUE_A(2);
  __syncthreads();

  // steady state: 2 chunks per iteration, 1 barrier per chunk,
  // 1-2 load-sets (64-128 KB/CU) outstanding at all times
  for (int c = 0; c < NCHUNK; c += 2) {
    // even step: compute chunk c (buf0), stage chunk c+1 (B -> buf1)
    CVT_WRITE_B();                               // chunk c+1
    COMPUTE(0);
    __builtin_amdgcn_sched_barrier(0);           // keep loads after MFMAs
    if (c + 3 < NCHUNK) ISSUE_B(c + 3);
    __syncthreads();
    // odd step: compute chunk c+1 (buf1), stage chunk c+2 (A -> buf0)
    if (c + 2 < NCHUNK) CVT_WRITE_A();           // chunk c+2
    COMPUTE(1);
    __builtin_amdgcn_sched_barrier(0);
    if (c + 4 < NCHUNK) ISSUE_A(c + 4);
    __syncthreads();
  }

  // mean partials: reduce 8 staging waves' column sums -> part[(b*4+s)][256]
  if (stager) *(float4*)&msum[w][c4 * 4] = ms;
  __syncthreads();
  if (t < 256) {
    float m = 0.f;
#pragma unroll
    for (int q = 0; q < 8; ++q) m += msum[q][t];
    part[(size_t)(b * 4 + s) * 256 + t] = m;      // raw sum (k_fin divides)
  }

  // covariance partial: wave subtile -> covp[s][b*3+tsel] (128x128 tile)
  if (alive) {
    float* cp = covp + ((size_t)(s * 192 + b * 3 + tsel) << 14);
#pragma unroll
    for (int m = 0; m < 4; ++m)
#pragma unroll
      for (int q = 0; q < 4; ++q) {
        int li = wr * 64 + m * 16 + fg * 4 + q;
#pragma unroll
        for (int n = 0; n < 4; ++n) {
          int lj = wc * 64 + n * 16 + fr;
          cp[li * 128 + lj] = acc[m][n][q];
        }
      }
  }
#undef ISSUE_A
#undef ISSUE_B
#undef CVT_WRITE
#undef CVT_WRITE_A
#undef CVT_WRITE_B
#undef COMPUTE
}

// ---------- k_fin: mean reduce + sum split partials + pack triu ----------
// grid = 64*3*2 = 384 blocks; each handles half a 128x128 tile, float4 reads.
__global__ __launch_bounds__(256) void k_fin(const float* __restrict__ covp,
                                             const float* __restrict__ part,
                                             float* __restrict__ out) {
  __shared__ float mean_s[256];
  int blk = blockIdx.x;
  int tile = blk >> 1, half = blk & 1;   // tile = b*3 + tsel
  int b = tile / 3, tsel = tile % 3;
  int ti = (tsel == 2) ? 1 : 0;
  int tj = (tsel == 0) ? 0 : 1;
  int t = threadIdx.x;

  float m = 0.f;
#pragma unroll
  for (int q = 0; q < NSPLIT; ++q) m += part[(size_t)(b * 4 + q) * 256 + t];
  mean_s[t] = m * (1.f / 4096.f);
  __syncthreads();

  const float4* cp0 = (const float4*)(covp + ((size_t)(0 * 192 + tile) << 14));
  const float4* cp1 = (const float4*)(covp + ((size_t)(1 * 192 + tile) << 14));
  const float4* cp2 = (const float4*)(covp + ((size_t)(2 * 192 + tile) << 14));
  const float4* cp3 = (const float4*)(covp + ((size_t)(3 * 192 + tile) << 14));

  float* ob = out + (size_t)b * NTRI;
  for (int e4 = t; e4 < 2048; e4 += 256) {
    int e = half * 8192 + (e4 << 2);
    int li = e >> 7, lj0 = e & 127;      // 4 consecutive lj in same row
    int i = ti * 128 + li;
    if (tj * 128 + lj0 + 3 < i) continue;   // whole quad below diagonal
    int q = e >> 2;
    float4 v0 = cp0[q], v1 = cp1[q], v2 = cp2[q], v3 = cp3[q];
    float sum[4] = {v0.x + v1.x + v2.x + v3.x, v0.y + v1.y + v2.y + v3.y,
                    v0.z + v1.z + v2.z + v3.z, v0.w + v1.w + v2.w + v3.w};
    float mi = mean_s[i];
    int ro = i * 256 - ((i * (i - 1)) >> 1) - i;
#pragma unroll
    for (int k = 0; k < 4; ++k) {
      int j = tj * 128 + lj0 + k;
      if (j >= i)
        ob[ro + j] = sum[k] * (1.f / 4096.f) - mi * mean_s[j];
    }
  }
}

// ---------- fallback: fp32 vector SYRK, no workspace ----------
__global__ __launch_bounds__(256) void k_cov_f32(const float* __restrict__ in,
                                                 float* __restrict__ out) {
  int blk = blockIdx.x;
  int b = blk / 10, ts = blk % 10;
  int ti, tj;
  if (ts < 4)      { ti = 0; tj = ts; }
  else if (ts < 7) { ti = 1; tj = ts - 3; }
  else if (ts < 9) { ti = 2; tj = ts - 5; }
  else             { ti = 3; tj = 3; }
  bool diag = (ti == tj);

  __shared__ float Pa[32][68];
  __shared__ float Pb[32][68];
  __shared__ float smA[64], smB[64];
  int t = threadIdx.x;
  if (t < 64) { smA[t] = 0.f; smB[t] = 0.f; }
  float acc[4][4] = {};
  int ri = t >> 4, rj = t & 15;
  const float* base = in + (size_t)b * NN * ND;

  for (int ks = 0; ks < 128; ++ks) {
    int nk = ks * 32;
    __syncthreads();
    for (int cc = t; cc < 512; cc += 256) {
      int r = cc >> 4, c4 = (cc & 15) << 2;
      *(float4*)&Pa[r][c4] = *(const float4*)(base + (size_t)(nk + r) * ND + ti * 64 + c4);
      if (!diag)
        *(float4*)&Pb[r][c4] = *(const float4*)(base + (size_t)(nk + r) * ND + tj * 64 + c4);
    }
    __syncthreads();
    if (t < 64) {
      float s = 0.f;
      for (int r = 0; r < 32; ++r) s += Pa[r][t];
      smA[t] += s;
    } else if (!diag && t < 128) {
      float s = 0.f;
      for (int r = 0; r < 32; ++r) s += Pb[r][t - 64];
      smB[t - 64] += s;
    }
    float(*Pbb)[68] = diag ? Pa : Pb;
    for (int k = 0; k < 32; ++k) {
      float4 a = *(const float4*)&Pa[k][ri << 2];
      float4 v = *(const float4*)&Pbb[k][rj << 2];
      float av[4] = {a.x, a.y, a.z, a.w};
      float bv[4] = {v.x, v.y, v.z, v.w};
#pragma unroll
      for (int e = 0; e < 4; ++e)
#pragma unroll
        for (int f = 0; f < 4; ++f) acc[e][f] += av[e] * bv[f];
    }
  }
  __syncthreads();
  const float inv = 1.f / 4096.f;
  const float* mB = diag ? smA : smB;
#pragma unroll
  for (int e = 0; e < 4; ++e) {
    int i = ti * 64 + (ri << 2) + e;
    float mi = smA[(ri << 2) + e] * inv;
    int ro = i * 256 - ((i * (i - 1)) >> 1) - i;
#pragma unroll
    for (int f = 0; f < 4; ++f) {
      int j = tj * 64 + (rj << 2) + f;
      if (j >= i)
        out[(size_t)b * NTRI + ro + j] = acc[e][f] * inv - mi * mB[(rj << 2) + f] * inv;
    }
  }
}

// ---------- launch ----------
extern "C" void kernel_launch(void* const* d_in, const int* in_sizes, int n_in,
                              void* d_out, int out_size, void* d_ws, size_t ws_size,
                              hipStream_t stream) {
  const float* in = (const float*)d_in[0];
  float* out = (float*)d_out;

  const size_t COVP_B = (size_t)NSPLIT * 192 * 16384 * 4;   // 50,331,648
  const size_t PART_B = (size_t)NB * NSPLIT * 256 * 4;      //     262,144
  const size_t need = COVP_B + PART_B;

  if (ws_size >= need) {
    float* covp = (float*)d_ws;
    float* part = (float*)((char*)d_ws + COVP_B);
    k_cov<<<NB * NSPLIT, 768, 0, stream>>>(in, covp, part);
    k_fin<<<NB * 3 * 2, 256, 0, stream>>>(covp, part, out);
  } else {
    k_cov_f32<<<NB * 10, 256, 0, stream>>>(in, out);
  }
}

// Round 7
// 70.630 us; speedup vs baseline: 1.0061x; 1.0061x over previous
//
#include <hip/hip_runtime.h>
#include <hip/hip_bf16.h>
#include <stdint.h>

typedef unsigned short u16;
typedef unsigned int   u32;

#define NB   64
#define NN   4096
#define ND   256
#define NTRI 32896   // 256*257/2
#define NSPLIT 4     // n-splits per batch
#define KROWS  1024  // rows per split
#define NCHUNK 16    // chunks per split (64 rows each)

// ---------- helpers ----------
__device__ __forceinline__ u32 cvtpk(float lo, float hi) {
  u32 r;
  asm("v_cvt_pk_bf16_f32 %0, %1, %2" : "=v"(r) : "v"(lo), "v"(hi));
  return r;
}

// Raw barrier: ds-writes drained (lgkmcnt only), global loads stay in flight.
// asm "memory" clobber = IR-level fence; sched_barrier(0) = MIR-level fence.
__device__ __forceinline__ void wg_barrier_lds() {
  asm volatile("s_waitcnt lgkmcnt(0)" ::: "memory");
  __builtin_amdgcn_s_barrier();
  __builtin_amdgcn_sched_barrier(0);
}

typedef __attribute__((ext_vector_type(8))) __bf16 bf16x8;
typedef __attribute__((ext_vector_type(4))) float  f32x4;

// ---------- fused: fp32 stream -> bf16 LDS transpose -> MFMA SYRK ----------
// grid = NB*NSPLIT = 256 blocks, 768 thr (12 waves).
// Depth-2 load pipeline (sets A/B) + raw lgkm-only barriers so global loads
// survive barriers -> memory queue never drains (T4 counted-wait principle).
__global__ __launch_bounds__(768) void k_cov(const float* __restrict__ in,
                                             float* __restrict__ covp,
                                             float* __restrict__ part) {
  __shared__ alignas(16) u16 Lt[2][2][256][32];   // 64 KB (2 buffers)
  __shared__ float msum[8][256];                  // 8 KB

  int blk = blockIdx.x;
  int b = blk >> 2, s = blk & 3;
  int t = threadIdx.x;
  int w = t >> 6, lane = t & 63;

  // compute roles: 12 waves = 3 triu tiles x 4 quadrants of 64x64
  int tsel = w >> 2;               // 0:(0,0) 1:(0,1) 2:(1,1)
  int quad = w & 3;
  int wr = quad >> 1, wc = quad & 1;
  int ti = (tsel == 2) ? 1 : 0;
  int tj = (tsel == 0) ? 0 : 1;
  bool diag = (ti == tj);
  bool alive = !(diag && quad == 2);   // (1,0) quadrant of diag tile: redundant
  int fr = lane & 15, fg = lane >> 4;
  int dpA = ti * 128 + wr * 64;
  int dpB = tj * 128 + wc * 64;

  // frag byte offsets within a [256][32] plane (16 KB)
  int aoffB[4], boffB[4];
  int jj = (fg ^ (fr >> 2)) << 4;
#pragma unroll
  for (int m = 0; m < 4; ++m) aoffB[m] = (dpA + m * 16 + fr) * 64 + jj;
#pragma unroll
  for (int n = 0; n < 4; ++n) boffB[n] = (dpB + n * 16 + fr) * 64 + jj;

  // staging roles (waves 0..7): wave w covers n_local rows w*8..w*8+7
  bool stager = (w < 8);
  int c4 = lane;                   // d-quad owned during cvt (rows d=4*c4+e)
  int ksw = w >> 2;                // ks-plane this wave fills (0/1)
  int xw = w & 3;                  // 16B n-chunk within plane
  int swz = ((xw ^ (c4 & 3)) << 4);

  f32x4 acc[4][4];
  f32x4 zero = {0.f, 0.f, 0.f, 0.f};
#pragma unroll
  for (int m = 0; m < 4; ++m)
#pragma unroll
    for (int n = 0; n < 4; ++n) acc[m][n] = zero;

  const float4* in4 = (const float4*)(in + (size_t)b * NN * ND);
  int rbase0 = (s * KROWS + w * 8) * 64 + c4;   // float4 index of chunk-0 row0

  float4 ms = make_float4(0.f, 0.f, 0.f, 0.f);
  float4 a0, a1, a2, a3, a4, a5, a6, a7;        // set A (even chunks)
  float4 b0, b1, b2, b3, b4, b5, b6, b7;        // set B (odd chunks)

#define ISSUE_A(C)                                              \
  if (stager) {                                                 \
    int rb = rbase0 + (C) * 4096;                               \
    a0 = in4[rb + 0 * 64]; a1 = in4[rb + 1 * 64];               \
    a2 = in4[rb + 2 * 64]; a3 = in4[rb + 3 * 64];               \
    a4 = in4[rb + 4 * 64]; a5 = in4[rb + 5 * 64];               \
    a6 = in4[rb + 6 * 64]; a7 = in4[rb + 7 * 64];               \
  }

#define ISSUE_B(C)                                              \
  if (stager) {                                                 \
    int rb = rbase0 + (C) * 4096;                               \
    b0 = in4[rb + 0 * 64]; b1 = in4[rb + 1 * 64];               \
    b2 = in4[rb + 2 * 64]; b3 = in4[rb + 3 * 64];               \
    b4 = in4[rb + 4 * 64]; b5 = in4[rb + 5 * 64];               \
    b6 = in4[rb + 6 * 64]; b7 = in4[rb + 7 * 64];               \
  }

// convert set r0..r7 and write to LDS buffer BUF (A -> buf0, B -> buf1)
#define CVT_WRITE(BUF, r0, r1, r2, r3, r4, r5, r6, r7)                        \
  if (stager) {                                                               \
    ms.x += r0.x + r1.x + r2.x + r3.x + r4.x + r5.x + r6.x + r7.x;            \
    ms.y += r0.y + r1.y + r2.y + r3.y + r4.y + r5.y + r6.y + r7.y;            \
    ms.z += r0.z + r1.z + r2.z + r3.z + r4.z + r5.z + r6.z + r7.z;            \
    ms.w += r0.w + r1.w + r2.w + r3.w + r4.w + r5.w + r6.w + r7.w;            \
    char* pl = (char*)&Lt[BUF][ksw][0][0] + swz;                              \
    *(uint4*)(pl + (c4 * 4 + 0) * 64) =                                       \
      make_uint4(cvtpk(r0.x, r1.x), cvtpk(r2.x, r3.x),                        \
                 cvtpk(r4.x, r5.x), cvtpk(r6.x, r7.x));                       \
    *(uint4*)(pl + (c4 * 4 + 1) * 64) =                                       \
      make_uint4(cvtpk(r0.y, r1.y), cvtpk(r2.y, r3.y),                        \
                 cvtpk(r4.y, r5.y), cvtpk(r6.y, r7.y));                       \
    *(uint4*)(pl + (c4 * 4 + 2) * 64) =                                       \
      make_uint4(cvtpk(r0.z, r1.z), cvtpk(r2.z, r3.z),                        \
                 cvtpk(r4.z, r5.z), cvtpk(r6.z, r7.z));                       \
    *(uint4*)(pl + (c4 * 4 + 3) * 64) =                                       \
      make_uint4(cvtpk(r0.w, r1.w), cvtpk(r2.w, r3.w),                        \
                 cvtpk(r4.w, r5.w), cvtpk(r6.w, r7.w));                       \
  }

#define CVT_WRITE_A() CVT_WRITE(0, a0, a1, a2, a3, a4, a5, a6, a7)
#define CVT_WRITE_B() CVT_WRITE(1, b0, b1, b2, b3, b4, b5, b6, b7)

#define COMPUTE(BUF)                                                          \
  if (alive) {                                                                \
    _Pragma("unroll")                                                         \
    for (int ks = 0; ks < 2; ++ks) {                                          \
      const char* pl = (const char*)&Lt[BUF][ks][0][0];                       \
      bf16x8 af[4], bfv[4];                                                   \
      _Pragma("unroll")                                                       \
      for (int m = 0; m < 4; ++m) af[m] = *(const bf16x8*)(pl + aoffB[m]);    \
      _Pragma("unroll")                                                       \
      for (int n = 0; n < 4; ++n) bfv[n] = *(const bf16x8*)(pl + boffB[n]);   \
      _Pragma("unroll")                                                       \
      for (int m = 0; m < 4; ++m)                                             \
        _Pragma("unroll")                                                     \
        for (int n = 0; n < 4; ++n)                                           \
          acc[m][n] = __builtin_amdgcn_mfma_f32_16x16x32_bf16(                \
              af[m], bfv[n], acc[m][n], 0, 0, 0);                             \
    }                                                                         \
  }

  // prologue: chunks 0(A),1(B) issued; chunk0 staged; chunk2(A) issued
  ISSUE_A(0);
  ISSUE_B(1);
  CVT_WRITE_A();                 // waits A's vmcnt (counted); B stays in flight
  ISSUE_A(2);
  wg_barrier_lds();

  // steady state: 2 chunks/iter, 1 raw barrier per chunk,
  // 64-128 KB of loads outstanding per CU at all times (no vmcnt drain)
  for (int c = 0; c < NCHUNK; c += 2) {
    // even step: compute chunk c (buf0), stage chunk c+1 (B -> buf1)
    CVT_WRITE_B();                               // chunk c+1
    COMPUTE(0);
    __builtin_amdgcn_sched_barrier(0);           // keep B-set dead thru MFMAs
    if (c + 3 < NCHUNK) ISSUE_B(c + 3);
    wg_barrier_lds();
    // odd step: compute chunk c+1 (buf1), stage chunk c+2 (A -> buf0)
    if (c + 2 < NCHUNK) CVT_WRITE_A();           // chunk c+2
    COMPUTE(1);
    __builtin_amdgcn_sched_barrier(0);
    if (c + 4 < NCHUNK) ISSUE_A(c + 4);
    wg_barrier_lds();
  }

  // epilogue: full barrier (drain everything once) before LDS reuse
  __syncthreads();

  // mean partials: reduce 8 staging waves' column sums -> part[(b*4+s)][256]
  if (stager) *(float4*)&msum[w][c4 * 4] = ms;
  __syncthreads();
  if (t < 256) {
    float m = 0.f;
#pragma unroll
    for (int q = 0; q < 8; ++q) m += msum[q][t];
    part[(size_t)(b * 4 + s) * 256 + t] = m;      // raw sum (k_fin divides)
  }

  // covariance partial: wave subtile -> covp[s][b*3+tsel] (128x128 tile)
  if (alive) {
    float* cp = covp + ((size_t)(s * 192 + b * 3 + tsel) << 14);
#pragma unroll
    for (int m = 0; m < 4; ++m)
#pragma unroll
      for (int q = 0; q < 4; ++q) {
        int li = wr * 64 + m * 16 + fg * 4 + q;
#pragma unroll
        for (int n = 0; n < 4; ++n) {
          int lj = wc * 64 + n * 16 + fr;
          cp[li * 128 + lj] = acc[m][n][q];
        }
      }
  }
#undef ISSUE_A
#undef ISSUE_B
#undef CVT_WRITE
#undef CVT_WRITE_A
#undef CVT_WRITE_B
#undef COMPUTE
}

// ---------- k_fin: mean reduce + sum split partials + pack triu ----------
// grid = 64*3*2 = 384 blocks; each handles half a 128x128 tile, float4 reads.
__global__ __launch_bounds__(256) void k_fin(const float* __restrict__ covp,
                                             const float* __restrict__ part,
                                             float* __restrict__ out) {
  __shared__ float mean_s[256];
  int blk = blockIdx.x;
  int tile = blk >> 1, half = blk & 1;   // tile = b*3 + tsel
  int b = tile / 3, tsel = tile % 3;
  int ti = (tsel == 2) ? 1 : 0;
  int tj = (tsel == 0) ? 0 : 1;
  int t = threadIdx.x;

  float m = 0.f;
#pragma unroll
  for (int q = 0; q < NSPLIT; ++q) m += part[(size_t)(b * 4 + q) * 256 + t];
  mean_s[t] = m * (1.f / 4096.f);
  __syncthreads();

  const float4* cp0 = (const float4*)(covp + ((size_t)(0 * 192 + tile) << 14));
  const float4* cp1 = (const float4*)(covp + ((size_t)(1 * 192 + tile) << 14));
  const float4* cp2 = (const float4*)(covp + ((size_t)(2 * 192 + tile) << 14));
  const float4* cp3 = (const float4*)(covp + ((size_t)(3 * 192 + tile) << 14));

  float* ob = out + (size_t)b * NTRI;
  for (int e4 = t; e4 < 2048; e4 += 256) {
    int e = half * 8192 + (e4 << 2);
    int li = e >> 7, lj0 = e & 127;      // 4 consecutive lj in same row
    int i = ti * 128 + li;
    if (tj * 128 + lj0 + 3 < i) continue;   // whole quad below diagonal
    int q = e >> 2;
    float4 v0 = cp0[q], v1 = cp1[q], v2 = cp2[q], v3 = cp3[q];
    float sum[4] = {v0.x + v1.x + v2.x + v3.x, v0.y + v1.y + v2.y + v3.y,
                    v0.z + v1.z + v2.z + v3.z, v0.w + v1.w + v2.w + v3.w};
    float mi = mean_s[i];
    int ro = i * 256 - ((i * (i - 1)) >> 1) - i;
#pragma unroll
    for (int k = 0; k < 4; ++k) {
      int j = tj * 128 + lj0 + k;
      if (j >= i)
        ob[ro + j] = sum[k] * (1.f / 4096.f) - mi * mean_s[j];
    }
  }
}

// ---------- fallback: fp32 vector SYRK, no workspace ----------
__global__ __launch_bounds__(256) void k_cov_f32(const float* __restrict__ in,
                                                 float* __restrict__ out) {
  int blk = blockIdx.x;
  int b = blk / 10, ts = blk % 10;
  int ti, tj;
  if (ts < 4)      { ti = 0; tj = ts; }
  else if (ts < 7) { ti = 1; tj = ts - 3; }
  else if (ts < 9) { ti = 2; tj = ts - 5; }
  else             { ti = 3; tj = 3; }
  bool diag = (ti == tj);

  __shared__ float Pa[32][68];
  __shared__ float Pb[32][68];
  __shared__ float smA[64], smB[64];
  int t = threadIdx.x;
  if (t < 64) { smA[t] = 0.f; smB[t] = 0.f; }
  float acc[4][4] = {};
  int ri = t >> 4, rj = t & 15;
  const float* base = in + (size_t)b * NN * ND;

  for (int ks = 0; ks < 128; ++ks) {
    int nk = ks * 32;
    __syncthreads();
    for (int cc = t; cc < 512; cc += 256) {
      int r = cc >> 4, c4 = (cc & 15) << 2;
      *(float4*)&Pa[r][c4] = *(const float4*)(base + (size_t)(nk + r) * ND + ti * 64 + c4);
      if (!diag)
        *(float4*)&Pb[r][c4] = *(const float4*)(base + (size_t)(nk + r) * ND + tj * 64 + c4);
    }
    __syncthreads();
    if (t < 64) {
      float s = 0.f;
      for (int r = 0; r < 32; ++r) s += Pa[r][t];
      smA[t] += s;
    } else if (!diag && t < 128) {
      float s = 0.f;
      for (int r = 0; r < 32; ++r) s += Pb[r][t - 64];
      smB[t - 64] += s;
    }
    float(*Pbb)[68] = diag ? Pa : Pb;
    for (int k = 0; k < 32; ++k) {
      float4 a = *(const float4*)&Pa[k][ri << 2];
      float4 v = *(const float4*)&Pbb[k][rj << 2];
      float av[4] = {a.x, a.y, a.z, a.w};
      float bv[4] = {v.x, v.y, v.z, v.w};
#pragma unroll
      for (int e = 0; e < 4; ++e)
#pragma unroll
        for (int f = 0; f < 4; ++f) acc[e][f] += av[e] * bv[f];
    }
  }
  __syncthreads();
  const float inv = 1.f / 4096.f;
  const float* mB = diag ? smA : smB;
#pragma unroll
  for (int e = 0; e < 4; ++e) {
    int i = ti * 64 + (ri << 2) + e;
    float mi = smA[(ri << 2) + e] * inv;
    int ro = i * 256 - ((i * (i - 1)) >> 1) - i;
#pragma unroll
    for (int f = 0; f < 4; ++f) {
      int j = tj * 64 + (rj << 2) + f;
      if (j >= i)
        out[(size_t)b * NTRI + ro + j] = acc[e][f] * inv - mi * mB[(rj << 2) + f] * inv;
    }
  }
}

// ---------- launch ----------
extern "C" void kernel_launch(void* const* d_in, const int* in_sizes, int n_in,
                              void* d_out, int out_size, void* d_ws, size_t ws_size,
                              hipStream_t stream) {
  const float* in = (const float*)d_in[0];
  float* out = (float*)d_out;

  const size_t COVP_B = (size_t)NSPLIT * 192 * 16384 * 4;   // 50,331,648
  const size_t PART_B = (size_t)NB * NSPLIT * 256 * 4;      //     262,144
  const size_t need = COVP_B + PART_B;

  if (ws_size >= need) {
    float* covp = (float*)d_ws;
    float* part = (float*)((char*)d_ws + COVP_B);
    k_cov<<<NB * NSPLIT, 768, 0, stream>>>(in, covp, part);
    k_fin<<<NB * 3 * 2, 256, 0, stream>>>(covp, part, out);
  } else {
    k_cov_f32<<<NB * 10, 256, 0, stream>>>(in, out);
  }
}

// Round 8
// 70.344 us; speedup vs baseline: 1.0102x; 1.0041x over previous
//
#include <hip/hip_runtime.h>
#include <hip/hip_bf16.h>
#include <stdint.h>

typedef unsigned short u16;
typedef unsigned int   u32;

#define NB   64
#define NN   4096
#define ND   256
#define NTRI 32896   // 256*257/2
#define NSPLIT 4     // n-splits per batch
#define KROWS  1024  // rows per split
#define NCHUNK 16    // chunks per split (64 rows each)

// ---------- helpers ----------
__device__ __forceinline__ u32 cvtpk(float lo, float hi) {
  u32 r;
  asm("v_cvt_pk_bf16_f32 %0, %1, %2" : "=v"(r) : "v"(lo), "v"(hi));
  return r;
}
__device__ __forceinline__ float b2f_lo(u32 v) {
  union { u32 u; float f; } x; x.u = v << 16; return x.f;
}
__device__ __forceinline__ float b2f_hi(u32 v) {
  union { u32 u; float f; } x; x.u = v & 0xffff0000u; return x.f;
}

typedef __attribute__((ext_vector_type(8))) __bf16 bf16x8;
typedef __attribute__((ext_vector_type(4))) float  f32x4;

// ---------- fused: fp32 stream -> bf16 LDS transpose -> MFMA SYRK ----------
// grid = NB*NSPLIT = 256 blocks, 768 thr (12 waves). Round-5 loop structure.
// covp partials stored BF16, col-major [lj][li] per 128x128 tile.
__global__ __launch_bounds__(768) void k_cov(const float* __restrict__ in,
                                             u16* __restrict__ covp,
                                             float* __restrict__ part) {
  __shared__ alignas(16) u16 Lt[2][2][256][32];   // 64 KB (2 buffers)
  __shared__ float msum[8][256];                  // 8 KB

  int blk = blockIdx.x;
  int b = blk >> 2, s = blk & 3;
  int t = threadIdx.x;
  int w = t >> 6, lane = t & 63;

  // compute roles: 12 waves = 3 triu tiles x 4 quadrants of 64x64
  int tsel = w >> 2;               // 0:(0,0) 1:(0,1) 2:(1,1)
  int quad = w & 3;
  int wr = quad >> 1, wc = quad & 1;
  int ti = (tsel == 2) ? 1 : 0;
  int tj = (tsel == 0) ? 0 : 1;
  bool diag = (ti == tj);
  bool alive = !(diag && quad == 2);   // (1,0) quadrant of diag tile: redundant
  int fr = lane & 15, fg = lane >> 4;
  int dpA = ti * 128 + wr * 64;
  int dpB = tj * 128 + wc * 64;

  // frag byte offsets within a [256][32] plane (16 KB)
  int aoffB[4], boffB[4];
  int jj = (fg ^ (fr >> 2)) << 4;
#pragma unroll
  for (int m = 0; m < 4; ++m) aoffB[m] = (dpA + m * 16 + fr) * 64 + jj;
#pragma unroll
  for (int n = 0; n < 4; ++n) boffB[n] = (dpB + n * 16 + fr) * 64 + jj;

  // staging roles (waves 0..7): wave w covers n_local rows w*8..w*8+7
  bool stager = (w < 8);
  int c4 = lane;                   // d-quad owned during cvt (rows d=4*c4+e)
  int ksw = w >> 2;                // ks-plane this wave fills (0/1)
  int xw = w & 3;                  // 16B n-chunk within plane
  int swz = ((xw ^ (c4 & 3)) << 4);

  f32x4 acc[4][4];
  f32x4 zero = {0.f, 0.f, 0.f, 0.f};
#pragma unroll
  for (int m = 0; m < 4; ++m)
#pragma unroll
    for (int n = 0; n < 4; ++n) acc[m][n] = zero;

  const float4* in4 = (const float4*)(in + (size_t)b * NN * ND);
  int rbase0 = (s * KROWS + w * 8) * 64 + c4;   // float4 index of chunk-0 row0

  float4 ms = make_float4(0.f, 0.f, 0.f, 0.f);
  float4 s0, s1, s2, s3, s4, s5, s6, s7;        // fp32 staging (1 set)
  uint4 q0, q1, q2, q3;                         // converted bf16 (1 set)

#define ISSUE(C)                                                \
  if (stager && (C) < NCHUNK) {                                 \
    int rb = rbase0 + (C) * 4096;                               \
    s0 = in4[rb + 0 * 64]; s1 = in4[rb + 1 * 64];               \
    s2 = in4[rb + 2 * 64]; s3 = in4[rb + 3 * 64];               \
    s4 = in4[rb + 4 * 64]; s5 = in4[rb + 5 * 64];               \
    s6 = in4[rb + 6 * 64]; s7 = in4[rb + 7 * 64];               \
  }

#define CVT()                                                                 \
  if (stager) {                                                               \
    ms.x += s0.x + s1.x + s2.x + s3.x + s4.x + s5.x + s6.x + s7.x;            \
    ms.y += s0.y + s1.y + s2.y + s3.y + s4.y + s5.y + s6.y + s7.y;            \
    ms.z += s0.z + s1.z + s2.z + s3.z + s4.z + s5.z + s6.z + s7.z;            \
    ms.w += s0.w + s1.w + s2.w + s3.w + s4.w + s5.w + s6.w + s7.w;            \
    q0 = make_uint4(cvtpk(s0.x, s1.x), cvtpk(s2.x, s3.x),                     \
                    cvtpk(s4.x, s5.x), cvtpk(s6.x, s7.x));                    \
    q1 = make_uint4(cvtpk(s0.y, s1.y), cvtpk(s2.y, s3.y),                     \
                    cvtpk(s4.y, s5.y), cvtpk(s6.y, s7.y));                    \
    q2 = make_uint4(cvtpk(s0.z, s1.z), cvtpk(s2.z, s3.z),                     \
                    cvtpk(s4.z, s5.z), cvtpk(s6.z, s7.z));                    \
    q3 = make_uint4(cvtpk(s0.w, s1.w), cvtpk(s2.w, s3.w),                     \
                    cvtpk(s4.w, s5.w), cvtpk(s6.w, s7.w));                    \
  }

#define WRITE(BUF)                                                            \
  if (stager) {                                                               \
    char* pl = (char*)&Lt[BUF][ksw][0][0] + swz;                              \
    *(uint4*)(pl + (c4 * 4 + 0) * 64) = q0;                                   \
    *(uint4*)(pl + (c4 * 4 + 1) * 64) = q1;                                   \
    *(uint4*)(pl + (c4 * 4 + 2) * 64) = q2;                                   \
    *(uint4*)(pl + (c4 * 4 + 3) * 64) = q3;                                   \
  }

#define COMPUTE(BUF)                                                          \
  if (alive) {                                                                \
    _Pragma("unroll")                                                         \
    for (int ks = 0; ks < 2; ++ks) {                                          \
      const char* pl = (const char*)&Lt[BUF][ks][0][0];                       \
      bf16x8 af[4], bfv[4];                                                   \
      _Pragma("unroll")                                                       \
      for (int m = 0; m < 4; ++m) af[m] = *(const bf16x8*)(pl + aoffB[m]);    \
      _Pragma("unroll")                                                       \
      for (int n = 0; n < 4; ++n) bfv[n] = *(const bf16x8*)(pl + boffB[n]);   \
      _Pragma("unroll")                                                       \
      for (int m = 0; m < 4; ++m)                                             \
        _Pragma("unroll")                                                     \
        for (int n = 0; n < 4; ++n)                                           \
          acc[m][n] = __builtin_amdgcn_mfma_f32_16x16x32_bf16(                \
              af[m], bfv[n], acc[m][n], 0, 0, 0);                             \
    }                                                                         \
  }

  // prologue: stage chunk 0, issue chunk 1
  ISSUE(0);
  CVT();
  ISSUE(1);
  WRITE(0);
  __syncthreads();
  // steady state: one barrier per chunk; loads 2 ahead
  for (int c = 0; c < NCHUNK - 1; ++c) {
    CVT();                      // chunk c+1
    ISSUE(c + 2);
    WRITE((c + 1) & 1);
    COMPUTE(c & 1);
    __syncthreads();
  }
  COMPUTE((NCHUNK - 1) & 1);    // final chunk

  // mean partials: reduce 8 staging waves' column sums -> part[(b*4+s)][256]
  if (stager) *(float4*)&msum[w][c4 * 4] = ms;
  __syncthreads();
  if (t < 256) {
    float m = 0.f;
#pragma unroll
    for (int q = 0; q < 8; ++q) m += msum[q][t];
    part[(size_t)(b * 4 + s) * 256 + t] = m;      // raw sum (k_fin divides)
  }

  // covariance partial: bf16, col-major [lj][li] (li fastest) per tile.
  // Lane packs its 4 consecutive li (fg*4+q) into one uint2 (8B aligned);
  // fg=0..3 x uint2 fill one contiguous 32B sector per lj.
  if (alive) {
    u16* cp = covp + ((size_t)(s * 192 + b * 3 + tsel) << 14);
#pragma unroll
    for (int m = 0; m < 4; ++m) {
      int liB = wr * 64 + m * 16 + fg * 4;
#pragma unroll
      for (int n = 0; n < 4; ++n) {
        int lj = wc * 64 + n * 16 + fr;
        uint2 pk;
        pk.x = cvtpk(acc[m][n][0], acc[m][n][1]);
        pk.y = cvtpk(acc[m][n][2], acc[m][n][3]);
        *(uint2*)(cp + lj * 128 + liB) = pk;
      }
    }
  }
#undef ISSUE
#undef CVT
#undef WRITE
#undef COMPUTE
}

// ---------- k_fin: mean reduce + sum bf16 split partials + pack triu ----------
// grid = 192 tiles x 2 halves = 384 blocks, 256 thr.
// Each wave reads one lj column (64 u32 = 128 li values), coalesced.
__global__ __launch_bounds__(256) void k_fin(const u16* __restrict__ covp,
                                             const float* __restrict__ part,
                                             float* __restrict__ out) {
  __shared__ float mean_s[256];
  int blk = blockIdx.x;
  int tile = blk >> 1, half = blk & 1;   // tile = b*3 + tsel
  int b = tile / 3, tsel = tile % 3;
  int ti = (tsel == 2) ? 1 : 0;
  int tj = (tsel == 0) ? 0 : 1;
  int t = threadIdx.x;

  float m = 0.f;
#pragma unroll
  for (int q = 0; q < NSPLIT; ++q) m += part[(size_t)(b * 4 + q) * 256 + t];
  mean_s[t] = m * (1.f / 4096.f);
  __syncthreads();

  const u32* cp0 = (const u32*)(covp + ((size_t)(0 * 192 + tile) << 14));
  const u32* cp1 = (const u32*)(covp + ((size_t)(1 * 192 + tile) << 14));
  const u32* cp2 = (const u32*)(covp + ((size_t)(2 * 192 + tile) << 14));
  const u32* cp3 = (const u32*)(covp + ((size_t)(3 * 192 + tile) << 14));

  const float inv = 1.f / 4096.f;
  float* ob = out + (size_t)b * NTRI;
#pragma unroll 4
  for (int k = 0; k < 16; ++k) {
    int e2 = half * 4096 + k * 256 + t;  // u32 index: lj*64 + li2
    int li2 = e2 & 63, lj = e2 >> 6;
    int i0 = ti * 128 + li2 * 2;
    int j  = tj * 128 + lj;
    if (j < i0) continue;                // both rows below diagonal: skip read
    u32 v0 = cp0[e2], v1 = cp1[e2], v2 = cp2[e2], v3 = cp3[e2];
    float slo = b2f_lo(v0) + b2f_lo(v1) + b2f_lo(v2) + b2f_lo(v3);
    float shi = b2f_hi(v0) + b2f_hi(v1) + b2f_hi(v2) + b2f_hi(v3);
    float mj = mean_s[j];
    int ro0 = i0 * 256 - ((i0 * (i0 - 1)) >> 1) - i0;
    ob[ro0 + j] = slo * inv - mean_s[i0] * mj;          // j >= i0 guaranteed
    int i1 = i0 + 1;
    if (j >= i1) {
      int ro1 = i1 * 256 - ((i1 * (i1 - 1)) >> 1) - i1;
      ob[ro1 + j] = shi * inv - mean_s[i1] * mj;
    }
  }
}

// ---------- fallback: fp32 vector SYRK, no workspace ----------
__global__ __launch_bounds__(256) void k_cov_f32(const float* __restrict__ in,
                                                 float* __restrict__ out) {
  int blk = blockIdx.x;
  int b = blk / 10, ts = blk % 10;
  int ti, tj;
  if (ts < 4)      { ti = 0; tj = ts; }
  else if (ts < 7) { ti = 1; tj = ts - 3; }
  else if (ts < 9) { ti = 2; tj = ts - 5; }
  else             { ti = 3; tj = 3; }
  bool diag = (ti == tj);

  __shared__ float Pa[32][68];
  __shared__ float Pb[32][68];
  __shared__ float smA[64], smB[64];
  int t = threadIdx.x;
  if (t < 64) { smA[t] = 0.f; smB[t] = 0.f; }
  float acc[4][4] = {};
  int ri = t >> 4, rj = t & 15;
  const float* base = in + (size_t)b * NN * ND;

  for (int ks = 0; ks < 128; ++ks) {
    int nk = ks * 32;
    __syncthreads();
    for (int cc = t; cc < 512; cc += 256) {
      int r = cc >> 4, c4 = (cc & 15) << 2;
      *(float4*)&Pa[r][c4] = *(const float4*)(base + (size_t)(nk + r) * ND + ti * 64 + c4);
      if (!diag)
        *(float4*)&Pb[r][c4] = *(const float4*)(base + (size_t)(nk + r) * ND + tj * 64 + c4);
    }
    __syncthreads();
    if (t < 64) {
      float s = 0.f;
      for (int r = 0; r < 32; ++r) s += Pa[r][t];
      smA[t] += s;
    } else if (!diag && t < 128) {
      float s = 0.f;
      for (int r = 0; r < 32; ++r) s += Pb[r][t - 64];
      smB[t - 64] += s;
    }
    float(*Pbb)[68] = diag ? Pa : Pb;
    for (int k = 0; k < 32; ++k) {
      float4 a = *(const float4*)&Pa[k][ri << 2];
      float4 v = *(const float4*)&Pbb[k][rj << 2];
      float av[4] = {a.x, a.y, a.z, a.w};
      float bv[4] = {v.x, v.y, v.z, v.w};
#pragma unroll
      for (int e = 0; e < 4; ++e)
#pragma unroll
        for (int f = 0; f < 4; ++f) acc[e][f] += av[e] * bv[f];
    }
  }
  __syncthreads();
  const float inv = 1.f / 4096.f;
  const float* mB = diag ? smA : smB;
#pragma unroll
  for (int e = 0; e < 4; ++e) {
    int i = ti * 64 + (ri << 2) + e;
    float mi = smA[(ri << 2) + e] * inv;
    int ro = i * 256 - ((i * (i - 1)) >> 1) - i;
#pragma unroll
    for (int f = 0; f < 4; ++f) {
      int j = tj * 64 + (rj << 2) + f;
      if (j >= i)
        out[(size_t)b * NTRI + ro + j] = acc[e][f] * inv - mi * mB[(rj << 2) + f] * inv;
    }
  }
}

// ---------- launch ----------
extern "C" void kernel_launch(void* const* d_in, const int* in_sizes, int n_in,
                              void* d_out, int out_size, void* d_ws, size_t ws_size,
                              hipStream_t stream) {
  const float* in = (const float*)d_in[0];
  float* out = (float*)d_out;

  const size_t COVP_B = (size_t)NSPLIT * 192 * 16384 * 2;   // 25,165,824 (bf16)
  const size_t PART_B = (size_t)NB * NSPLIT * 256 * 4;      //     262,144
  const size_t need = COVP_B + PART_B;

  if (ws_size >= need) {
    u16*   covp = (u16*)d_ws;
    float* part = (float*)((char*)d_ws + COVP_B);
    k_cov<<<NB * NSPLIT, 768, 0, stream>>>(in, covp, part);
    k_fin<<<NB * 3 * 2, 256, 0, stream>>>(covp, part, out);
  } else {
    k_cov_f32<<<NB * 10, 256, 0, stream>>>(in, out);
  }
}

// Round 9
// 61.328 us; speedup vs baseline: 1.1587x; 1.1470x over previous
//
#include <hip/hip_runtime.h>
#include <hip/hip_bf16.h>
#include <stdint.h>

typedef unsigned short u16;
typedef unsigned int   u32;

#define NB   64
#define NN   4096
#define ND   256
#define NTRI 32896   // 256*257/2
#define NSPLIT 4     // n-splits per batch
#define KROWS  1024  // rows per split
#define NCHUNK 16    // chunks per split (64 rows each)

// ---------- helpers ----------
__device__ __forceinline__ u32 cvtpk(float lo, float hi) {
  u32 r;
  asm("v_cvt_pk_bf16_f32 %0, %1, %2" : "=v"(r) : "v"(lo), "v"(hi));
  return r;
}
__device__ __forceinline__ float b2f_lo(u32 v) {
  union { u32 u; float f; } x; x.u = v << 16; return x.f;
}
__device__ __forceinline__ float b2f_hi(u32 v) {
  union { u32 u; float f; } x; x.u = v & 0xffff0000u; return x.f;
}

typedef __attribute__((ext_vector_type(8))) __bf16 bf16x8;
typedef __attribute__((ext_vector_type(4))) float  f32x4;

// ---------- fused: fp32 stream -> bf16 LDS transpose -> MFMA SYRK ----------
// grid = NB*NSPLIT = 256 blocks, 768 thr (12 waves). (r8 kernel, unchanged)
// covp partials stored BF16, col-major [lj][li] per 128x128 tile.
__global__ __launch_bounds__(768) void k_cov(const float* __restrict__ in,
                                             u16* __restrict__ covp,
                                             float* __restrict__ part) {
  __shared__ alignas(16) u16 Lt[2][2][256][32];   // 64 KB (2 buffers)
  __shared__ float msum[8][256];                  // 8 KB

  int blk = blockIdx.x;
  int b = blk >> 2, s = blk & 3;
  int t = threadIdx.x;
  int w = t >> 6, lane = t & 63;

  // compute roles: 12 waves = 3 triu tiles x 4 quadrants of 64x64
  int tsel = w >> 2;               // 0:(0,0) 1:(0,1) 2:(1,1)
  int quad = w & 3;
  int wr = quad >> 1, wc = quad & 1;
  int ti = (tsel == 2) ? 1 : 0;
  int tj = (tsel == 0) ? 0 : 1;
  bool diag = (ti == tj);
  bool alive = !(diag && quad == 2);   // (1,0) quadrant of diag tile: redundant
  int fr = lane & 15, fg = lane >> 4;
  int dpA = ti * 128 + wr * 64;
  int dpB = tj * 128 + wc * 64;

  // frag byte offsets within a [256][32] plane (16 KB)
  int aoffB[4], boffB[4];
  int jj = (fg ^ (fr >> 2)) << 4;
#pragma unroll
  for (int m = 0; m < 4; ++m) aoffB[m] = (dpA + m * 16 + fr) * 64 + jj;
#pragma unroll
  for (int n = 0; n < 4; ++n) boffB[n] = (dpB + n * 16 + fr) * 64 + jj;

  // staging roles (waves 0..7): wave w covers n_local rows w*8..w*8+7
  bool stager = (w < 8);
  int c4 = lane;                   // d-quad owned during cvt (rows d=4*c4+e)
  int ksw = w >> 2;                // ks-plane this wave fills (0/1)
  int xw = w & 3;                  // 16B n-chunk within plane
  int swz = ((xw ^ (c4 & 3)) << 4);

  f32x4 acc[4][4];
  f32x4 zero = {0.f, 0.f, 0.f, 0.f};
#pragma unroll
  for (int m = 0; m < 4; ++m)
#pragma unroll
    for (int n = 0; n < 4; ++n) acc[m][n] = zero;

  const float4* in4 = (const float4*)(in + (size_t)b * NN * ND);
  int rbase0 = (s * KROWS + w * 8) * 64 + c4;   // float4 index of chunk-0 row0

  float4 ms = make_float4(0.f, 0.f, 0.f, 0.f);
  float4 s0, s1, s2, s3, s4, s5, s6, s7;        // fp32 staging (1 set)
  uint4 q0, q1, q2, q3;                         // converted bf16 (1 set)

#define ISSUE(C)                                                \
  if (stager && (C) < NCHUNK) {                                 \
    int rb = rbase0 + (C) * 4096;                               \
    s0 = in4[rb + 0 * 64]; s1 = in4[rb + 1 * 64];               \
    s2 = in4[rb + 2 * 64]; s3 = in4[rb + 3 * 64];               \
    s4 = in4[rb + 4 * 64]; s5 = in4[rb + 5 * 64];               \
    s6 = in4[rb + 6 * 64]; s7 = in4[rb + 7 * 64];               \
  }

#define CVT()                                                                 \
  if (stager) {                                                               \
    ms.x += s0.x + s1.x + s2.x + s3.x + s4.x + s5.x + s6.x + s7.x;            \
    ms.y += s0.y + s1.y + s2.y + s3.y + s4.y + s5.y + s6.y + s7.y;            \
    ms.z += s0.z + s1.z + s2.z + s3.z + s4.z + s5.z + s6.z + s7.z;            \
    ms.w += s0.w + s1.w + s2.w + s3.w + s4.w + s5.w + s6.w + s7.w;            \
    q0 = make_uint4(cvtpk(s0.x, s1.x), cvtpk(s2.x, s3.x),                     \
                    cvtpk(s4.x, s5.x), cvtpk(s6.x, s7.x));                    \
    q1 = make_uint4(cvtpk(s0.y, s1.y), cvtpk(s2.y, s3.y),                     \
                    cvtpk(s4.y, s5.y), cvtpk(s6.y, s7.y));                    \
    q2 = make_uint4(cvtpk(s0.z, s1.z), cvtpk(s2.z, s3.z),                     \
                    cvtpk(s4.z, s5.z), cvtpk(s6.z, s7.z));                    \
    q3 = make_uint4(cvtpk(s0.w, s1.w), cvtpk(s2.w, s3.w),                     \
                    cvtpk(s4.w, s5.w), cvtpk(s6.w, s7.w));                    \
  }

#define WRITE(BUF)                                                            \
  if (stager) {                                                               \
    char* pl = (char*)&Lt[BUF][ksw][0][0] + swz;                              \
    *(uint4*)(pl + (c4 * 4 + 0) * 64) = q0;                                   \
    *(uint4*)(pl + (c4 * 4 + 1) * 64) = q1;                                   \
    *(uint4*)(pl + (c4 * 4 + 2) * 64) = q2;                                   \
    *(uint4*)(pl + (c4 * 4 + 3) * 64) = q3;                                   \
  }

#define COMPUTE(BUF)                                                          \
  if (alive) {                                                                \
    _Pragma("unroll")                                                         \
    for (int ks = 0; ks < 2; ++ks) {                                          \
      const char* pl = (const char*)&Lt[BUF][ks][0][0];                       \
      bf16x8 af[4], bfv[4];                                                   \
      _Pragma("unroll")                                                       \
      for (int m = 0; m < 4; ++m) af[m] = *(const bf16x8*)(pl + aoffB[m]);    \
      _Pragma("unroll")                                                       \
      for (int n = 0; n < 4; ++n) bfv[n] = *(const bf16x8*)(pl + boffB[n]);   \
      _Pragma("unroll")                                                       \
      for (int m = 0; m < 4; ++m)                                             \
        _Pragma("unroll")                                                     \
        for (int n = 0; n < 4; ++n)                                           \
          acc[m][n] = __builtin_amdgcn_mfma_f32_16x16x32_bf16(                \
              af[m], bfv[n], acc[m][n], 0, 0, 0);                             \
    }                                                                         \
  }

  // prologue: stage chunk 0, issue chunk 1
  ISSUE(0);
  CVT();
  ISSUE(1);
  WRITE(0);
  __syncthreads();
  // steady state: one barrier per chunk; loads 2 ahead
  for (int c = 0; c < NCHUNK - 1; ++c) {
    CVT();                      // chunk c+1
    ISSUE(c + 2);
    WRITE((c + 1) & 1);
    COMPUTE(c & 1);
    __syncthreads();
  }
  COMPUTE((NCHUNK - 1) & 1);    // final chunk

  // mean partials: reduce 8 staging waves' column sums -> part[(b*4+s)][256]
  if (stager) *(float4*)&msum[w][c4 * 4] = ms;
  __syncthreads();
  if (t < 256) {
    float m = 0.f;
#pragma unroll
    for (int q = 0; q < 8; ++q) m += msum[q][t];
    part[(size_t)(b * 4 + s) * 256 + t] = m;      // raw sum (k_fin divides)
  }

  // covariance partial: bf16, col-major [lj][li] (li fastest) per tile.
  if (alive) {
    u16* cp = covp + ((size_t)(s * 192 + b * 3 + tsel) << 14);
#pragma unroll
    for (int m = 0; m < 4; ++m) {
      int liB = wr * 64 + m * 16 + fg * 4;
#pragma unroll
      for (int n = 0; n < 4; ++n) {
        int lj = wc * 64 + n * 16 + fr;
        uint2 pk;
        pk.x = cvtpk(acc[m][n][0], acc[m][n][1]);
        pk.y = cvtpk(acc[m][n][2], acc[m][n][3]);
        *(uint2*)(cp + lj * 128 + liB) = pk;
      }
    }
  }
#undef ISSUE
#undef CVT
#undef WRITE
#undef COMPUTE
}

// ---------- k_fin: coalesced col-major reads -> LDS transpose -> row-major
// triu writes. grid = 192 tiles x 2 halves = 384 blocks, 256 thr.
__global__ __launch_bounds__(256) void k_fin(const u16* __restrict__ covp,
                                             const float* __restrict__ part,
                                             float* __restrict__ out) {
  __shared__ float mean_s[256];
  __shared__ float Lf[64][130];          // half-tile transposed, +2 pad
  int blk = blockIdx.x;
  int tile = blk >> 1, half = blk & 1;   // tile = b*3 + tsel
  int b = tile / 3, tsel = tile % 3;
  int ti = (tsel == 2) ? 1 : 0;
  int tj = (tsel == 0) ? 0 : 1;
  int t = threadIdx.x;

  float m = 0.f;
#pragma unroll
  for (int q = 0; q < NSPLIT; ++q) m += part[(size_t)(b * 4 + q) * 256 + t];
  mean_s[t] = m * (1.f / 4096.f);

  const u32* cp0 = (const u32*)(covp + ((size_t)(0 * 192 + tile) << 14));
  const u32* cp1 = (const u32*)(covp + ((size_t)(1 * 192 + tile) << 14));
  const u32* cp2 = (const u32*)(covp + ((size_t)(2 * 192 + tile) << 14));
  const u32* cp3 = (const u32*)(covp + ((size_t)(3 * 192 + tile) << 14));

  // phase 1: read col-major (coalesced u32), sum splits, transpose into LDS.
  // covp u32 index = lj*64 + li2 (li2 = li/2, li2 = half*32 + li2h).
#pragma unroll 4
  for (int k = 0; k < 16; ++k) {
    int idx  = k * 256 + t;              // 0..4095 over [lj 0..127][li2h 0..31]
    int li2h = idx & 31, lj = idx >> 5;
    int e2 = lj * 64 + half * 32 + li2h;
    u32 v0 = cp0[e2], v1 = cp1[e2], v2 = cp2[e2], v3 = cp3[e2];
    Lf[li2h * 2 + 0][lj] = b2f_lo(v0) + b2f_lo(v1) + b2f_lo(v2) + b2f_lo(v3);
    Lf[li2h * 2 + 1][lj] = b2f_hi(v0) + b2f_hi(v1) + b2f_hi(v2) + b2f_hi(v3);
  }
  __syncthreads();

  // phase 2: row-major writes, contiguous 256B per wave-instruction.
  const float inv = 1.f / 4096.f;
  float* ob = out + (size_t)b * NTRI;
#pragma unroll 4
  for (int e0 = 0; e0 < 8192; e0 += 256) {
    int e = e0 + t;
    int ll = e >> 7, lj = e & 127;       // row within half, col
    int i = ti * 128 + half * 64 + ll;
    int j = tj * 128 + lj;
    if (j >= i) {
      int ro = i * 256 - ((i * (i - 1)) >> 1) - i;
      ob[ro + j] = Lf[ll][lj] * inv - mean_s[i] * mean_s[j];
    }
  }
}

// ---------- fallback: fp32 vector SYRK, no workspace ----------
__global__ __launch_bounds__(256) void k_cov_f32(const float* __restrict__ in,
                                                 float* __restrict__ out) {
  int blk = blockIdx.x;
  int b = blk / 10, ts = blk % 10;
  int ti, tj;
  if (ts < 4)      { ti = 0; tj = ts; }
  else if (ts < 7) { ti = 1; tj = ts - 3; }
  else if (ts < 9) { ti = 2; tj = ts - 5; }
  else             { ti = 3; tj = 3; }
  bool diag = (ti == tj);

  __shared__ float Pa[32][68];
  __shared__ float Pb[32][68];
  __shared__ float smA[64], smB[64];
  int t = threadIdx.x;
  if (t < 64) { smA[t] = 0.f; smB[t] = 0.f; }
  float acc[4][4] = {};
  int ri = t >> 4, rj = t & 15;
  const float* base = in + (size_t)b * NN * ND;

  for (int ks = 0; ks < 128; ++ks) {
    int nk = ks * 32;
    __syncthreads();
    for (int cc = t; cc < 512; cc += 256) {
      int r = cc >> 4, c4 = (cc & 15) << 2;
      *(float4*)&Pa[r][c4] = *(const float4*)(base + (size_t)(nk + r) * ND + ti * 64 + c4);
      if (!diag)
        *(float4*)&Pb[r][c4] = *(const float4*)(base + (size_t)(nk + r) * ND + tj * 64 + c4);
    }
    __syncthreads();
    if (t < 64) {
      float s = 0.f;
      for (int r = 0; r < 32; ++r) s += Pa[r][t];
      smA[t] += s;
    } else if (!diag && t < 128) {
      float s = 0.f;
      for (int r = 0; r < 32; ++r) s += Pb[r][t - 64];
      smB[t - 64] += s;
    }
    float(*Pbb)[68] = diag ? Pa : Pb;
    for (int k = 0; k < 32; ++k) {
      float4 a = *(const float4*)&Pa[k][ri << 2];
      float4 v = *(const float4*)&Pbb[k][rj << 2];
      float av[4] = {a.x, a.y, a.z, a.w};
      float bv[4] = {v.x, v.y, v.z, v.w};
#pragma unroll
      for (int e = 0; e < 4; ++e)
#pragma unroll
        for (int f = 0; f < 4; ++f) acc[e][f] += av[e] * bv[f];
    }
  }
  __syncthreads();
  const float inv = 1.f / 4096.f;
  const float* mB = diag ? smA : smB;
#pragma unroll
  for (int e = 0; e < 4; ++e) {
    int i = ti * 64 + (ri << 2) + e;
    float mi = smA[(ri << 2) + e] * inv;
    int ro = i * 256 - ((i * (i - 1)) >> 1) - i;
#pragma unroll
    for (int f = 0; f < 4; ++f) {
      int j = tj * 64 + (rj << 2) + f;
      if (j >= i)
        out[(size_t)b * NTRI + ro + j] = acc[e][f] * inv - mi * mB[(rj << 2) + f] * inv;
    }
  }
}

// ---------- launch ----------
extern "C" void kernel_launch(void* const* d_in, const int* in_sizes, int n_in,
                              void* d_out, int out_size, void* d_ws, size_t ws_size,
                              hipStream_t stream) {
  const float* in = (const float*)d_in[0];
  float* out = (float*)d_out;

  const size_t COVP_B = (size_t)NSPLIT * 192 * 16384 * 2;   // 25,165,824 (bf16)
  const size_t PART_B = (size_t)NB * NSPLIT * 256 * 4;      //     262,144
  const size_t need = COVP_B + PART_B;

  if (ws_size >= need) {
    u16*   covp = (u16*)d_ws;
    float* part = (float*)((char*)d_ws + COVP_B);
    k_cov<<<NB * NSPLIT, 768, 0, stream>>>(in, covp, part);
    k_fin<<<NB * 3 * 2, 256, 0, stream>>>(covp, part, out);
  } else {
    k_cov_f32<<<NB * 10, 256, 0, stream>>>(in, out);
  }
}